// Round 10
// baseline (87.782 us; speedup 1.0000x reference)
//
#include <hip/hip_runtime.h>
#include <hip/hip_bf16.h>
#include <math.h>

#define BSZ 512
#define FDIM 512
#define NK 32
#define DD 16
#define NDIM (NK*DD)      // 512
#define OUTW (FDIM + NK)  // 544

typedef __attribute__((ext_vector_type(8))) short short8;   // bf16x8 frag
typedef __attribute__((ext_vector_type(4))) float float4v;  // C/D frag

static __device__ __forceinline__ unsigned short f2bfu(float f) {
  return __builtin_bit_cast(unsigned short, __float2bfloat16(f));
}

// ---------------------------------------------------------------------------
// Kernel 0 (k_prep): VERBATIM R9 (tripwire-proven). The only cold-HBM
// toucher; eats the time-fixed ~25us post-fill drain wall no matter what.
// Produces bf16 xbf (row-major) + tbf (T transposed), x->out copy,
// feats-zero.
// ---------------------------------------------------------------------------
__global__ __launch_bounds__(256) void k_prep(
    const float* __restrict__ x, const float* __restrict__ T,
    unsigned short* __restrict__ xbf, unsigned short* __restrict__ tbf,
    float* __restrict__ out) {
  const int t = threadIdx.x, b = blockIdx.x;
  if (b < 64) {
    __shared__ unsigned short lt[64][65];  // +1 pad: transpose bounce
    const int tr = b >> 3, tc = b & 7;     // 64x64 tile of T
    const float4* T4 = (const float4*)T;   // T row = 128 float4
#pragma unroll
    for (int qi = 0; qi < 4; ++qi) {
      const int idx = qi * 256 + t;        // 0..1023
      const int rr = idx >> 4, c4 = idx & 15;
      const float4 v = T4[(size_t)(tr * 64 + rr) * 128 + tc * 16 + c4];
      lt[c4 * 4 + 0][rr] = f2bfu(v.x);
      lt[c4 * 4 + 1][rr] = f2bfu(v.y);
      lt[c4 * 4 + 2][rr] = f2bfu(v.z);
      lt[c4 * 4 + 3][rr] = f2bfu(v.w);
    }
    __syncthreads();
#pragma unroll
    for (int qi = 0; qi < 8; ++qi) {
      const int idx = qi * 256 + t;        // 0..2047 (ushort2 units)
      const int cl = idx >> 5, sg = idx & 31;
      ushort2 p;
      p.x = lt[cl][sg * 2];
      p.y = lt[cl][sg * 2 + 1];
      *(ushort2*)(tbf + (size_t)(tc * 64 + cl) * 512 + tr * 64 + sg * 2) = p;
    }
  } else {
    const int bb = b - 64;
    const float4* x4 = (const float4*)x;   // 65536 float4
#pragma unroll
    for (int qi = 0; qi < 4; ++qi) {
      const int i = bb * 1024 + qi * 256 + t;   // 0..65535, coalesced
      const float4 v = x4[i];
      const int orow = i >> 7, c4 = i & 127;
      *(float4*)(out + (size_t)orow * OUTW + c4 * 4) = v;  // x -> out
      ushort4 u;
      u.x = f2bfu(v.x); u.y = f2bfu(v.y); u.z = f2bfu(v.z); u.w = f2bfu(v.w);
      *(ushort4*)(xbf + (size_t)i * 4) = u;                // bf16 x
    }
    const int idx2 = bb * 256 + t;          // 0..16383: zero feats cols
    out[(size_t)(idx2 >> 5) * OUTW + FDIM + (idx2 & 31)] = 0.f;
  }
}

// ---------------------------------------------------------------------------
// Kernel 1 (k_gemm): VERBATIM R9 (tripwire-proven, ~2us). m = xbf @ tbf^T
// via bf16 MFMA on L2/IC-hot ws buffers; 2 dwordx4 loads per MFMA.
// ---------------------------------------------------------------------------
__global__ __launch_bounds__(256, 4) void k_gemm(
    const unsigned short* __restrict__ xbf,
    const unsigned short* __restrict__ tbf, float* __restrict__ m) {
  const int t  = threadIdx.x;
  const int b  = blockIdx.x;
  const int rg = b >> 5, cg = b & 31;
  const int r0 = rg * 16, c0 = cg * 16;
  const int lane = t & 63;
  const int w    = __builtin_amdgcn_readfirstlane(t >> 6);  // K-chunk 0..3
  const int mi   = lane & 15;
  const int q    = lane >> 4;

  const unsigned short* __restrict__ xa =
      xbf + (size_t)(r0 + mi) * FDIM + 128 * w + 8 * q;
  const unsigned short* __restrict__ tb =
      tbf + (size_t)(c0 + mi) * FDIM + 128 * w + 8 * q;

  short8 af[4], bf[4];
#pragma unroll
  for (int j = 0; j < 4; ++j) {          // batch all 8 loads before use
    af[j] = *(const short8*)(xa + 32 * j);
    bf[j] = *(const short8*)(tb + 32 * j);
  }
  float4v acc = {0.f, 0.f, 0.f, 0.f};
#pragma unroll
  for (int j = 0; j < 4; ++j)
    acc = __builtin_amdgcn_mfma_f32_16x16x32_bf16(af[j], bf[j], acc, 0, 0, 0);

  __shared__ float red[4][16][16];
#pragma unroll
  for (int r = 0; r < 4; ++r) red[w][q * 4 + r][mi] = acc[r];
  __syncthreads();
  {
    const int orow = t >> 4, ocol = t & 15;
    const float s = red[0][orow][ocol] + red[1][orow][ocol] +
                    red[2][orow][ocol] + red[3][orow][ocol];
    m[(size_t)(r0 + orow) * NDIM + c0 + ocol] = s;
  }
}

// ---------------------------------------------------------------------------
// Kernel 2 (k_dist): register-tiled 4i x 4j. R9's version paid 4 uniform
// ds_read_b128 per (i,j) pair (LDS ~= VALU cycles, serialized -> ~6us).
// Here each B-row read feeds FOUR i's (LDS share /4); A-fragments live in
// registers (4x16 = 64 VGPR). grid 2048 = 8 ig x 32 k x 8 jo; 256 thr =
// 4 waves; block = 64 i x 64 j. Wave: lane&15 = i-tile (4 rows),
// (lane>>4)+4w = j-tile (4 rows). Per thread: 4 jj x (4 b128 + 128 VALU)
// + 16 exp. Reduce: shfl_xor(16,32) over j-tiles in wave -> LDS across
// waves -> atomicAdd (8 jo contenders; feats zeroed by k_prep).
// ---------------------------------------------------------------------------
__global__ __launch_bounds__(256, 4) void k_dist(
    const float* __restrict__ m, float* __restrict__ out) {
  __shared__ float As[64 * DD];    // 4 KB: i-rows
  __shared__ float Bs[64 * DD];    // 4 KB: j-rows
  __shared__ float red[4][4][16];  // 1 KB: [wave][ii][it]
  const int t   = threadIdx.x;
  const int bid = blockIdx.x;          // 2048 = 8 ig x 32 k x 8 jo
  const int ig  = bid >> 8;            // 0..7
  const int k   = (bid >> 3) & 31;     // 0..31
  const int jo  = bid & 7;             // j octant (64 j's)
  const int lane = t & 63;
  const int w    = t >> 6;             // wave 0..3

  // stage As/Bs: one float4 each per thread, coalesced (m is L2-hot)
  {
    const int row = t >> 2, part = t & 3;
    *(float4*)&As[row * DD + part * 4] = *(const float4*)(
        m + (size_t)(ig * 64 + row) * NDIM + k * DD + part * 4);
    *(float4*)&Bs[row * DD + part * 4] = *(const float4*)(
        m + (size_t)(jo * 64 + row) * NDIM + k * DD + part * 4);
  }
  __syncthreads();

  const int it = lane & 15;                 // i-tile: rows it*4..+4
  const int jt = (lane >> 4) + 4 * w;       // j-tile 0..15: rows jt*4..+4

  // A fragments in registers: 4 rows x 16 d
  float a4[4][DD];
#pragma unroll
  for (int ii = 0; ii < 4; ++ii) {
    const float4* ap = (const float4*)&As[(it * 4 + ii) * DD];
#pragma unroll
    for (int p = 0; p < 4; ++p) {
      const float4 v = ap[p];
      a4[ii][p * 4 + 0] = v.x; a4[ii][p * 4 + 1] = v.y;
      a4[ii][p * 4 + 2] = v.z; a4[ii][p * 4 + 3] = v.w;
    }
  }

  float dist[4][4];
#pragma unroll
  for (int ii = 0; ii < 4; ++ii)
#pragma unroll
    for (int jj = 0; jj < 4; ++jj) dist[ii][jj] = 0.f;

#pragma unroll
  for (int jj = 0; jj < 4; ++jj) {
    const float4* bp = (const float4*)&Bs[(jt * 4 + jj) * DD];
    const float4 b0 = bp[0], b1 = bp[1], b2 = bp[2], b3 = bp[3];
    float bb[DD];
    bb[0]=b0.x; bb[1]=b0.y; bb[2]=b0.z;  bb[3]=b0.w;
    bb[4]=b1.x; bb[5]=b1.y; bb[6]=b1.z;  bb[7]=b1.w;
    bb[8]=b2.x; bb[9]=b2.y; bb[10]=b2.z; bb[11]=b2.w;
    bb[12]=b3.x;bb[13]=b3.y;bb[14]=b3.z; bb[15]=b3.w;
#pragma unroll
    for (int ii = 0; ii < 4; ++ii) {
      float d = 0.f;
#pragma unroll
      for (int dd = 0; dd < DD; ++dd) d += fabsf(a4[ii][dd] - bb[dd]);
      dist[ii][jj] = d;
    }
  }

  float f4[4];
#pragma unroll
  for (int ii = 0; ii < 4; ++ii) {
    f4[ii] = __expf(-dist[ii][0]) + __expf(-dist[ii][1]) +
             __expf(-dist[ii][2]) + __expf(-dist[ii][3]);
    // combine the wave's 4 j-tiles (lanes differing in lane>>4)
    f4[ii] += __shfl_xor(f4[ii], 16);
    f4[ii] += __shfl_xor(f4[ii], 32);
  }
  if (lane < 16) {
#pragma unroll
    for (int ii = 0; ii < 4; ++ii) red[w][ii][lane] = f4[ii];
  }
  __syncthreads();
  if (t < 64) {
    // i_local = (t>>2)*4 + (t&3) == t
    const float s = red[0][t & 3][t >> 2] + red[1][t & 3][t >> 2] +
                    red[2][t & 3][t >> 2] + red[3][t & 3][t >> 2];
    atomicAdd(out + (size_t)(ig * 64 + t) * OUTW + FDIM + k, s);
  }
}

extern "C" void kernel_launch(void* const* d_in, const int* in_sizes, int n_in,
                              void* d_out, int out_size, void* d_ws,
                              size_t ws_size, hipStream_t stream) {
  (void)in_sizes; (void)n_in; (void)out_size; (void)ws_size;
  const float* x = (const float*)d_in[0];
  const float* T = (const float*)d_in[1];
  float* out = (float*)d_out;
  float* m = (float*)d_ws;                                   // 1 MB fp32
  unsigned short* xbf = (unsigned short*)((char*)d_ws + (size_t)BSZ * NDIM * 4);
  unsigned short* tbf = xbf + (size_t)BSZ * FDIM;            // +512 KB each

  hipLaunchKernelGGL(k_prep, dim3(128), dim3(256), 0, stream,
                     x, T, xbf, tbf, out);
  hipLaunchKernelGGL(k_gemm, dim3(1024), dim3(256), 0, stream, xbf, tbf, m);
  hipLaunchKernelGGL(k_dist, dim3(2048), dim3(256), 0, stream, m, out);
}